// Round 1
// baseline (33.915 us; speedup 1.0000x reference)
//
#include <hip/hip_runtime.h>

// ---------------------------------------------------------------------------
// Quantum conv2d: per output pixel, simulate a 4-wire (16-dim) circuit.
// State kept entirely in registers (sr/si), all indices compile-time.
// ---------------------------------------------------------------------------

template<int STRIDE>
__device__ __forceinline__ void apply_gate(float* sr, float* si,
        float m00r, float m00i, float m01r, float m01i,
        float m10r, float m10i, float m11r, float m11i) {
    #pragma unroll
    for (int m0 = 0; m0 < 16; ++m0) {
        if (m0 & STRIDE) continue;
        const int m1 = m0 | STRIDE;
        const float ar = sr[m0], ai = si[m0], br = sr[m1], bi = si[m1];
        sr[m0] = m00r*ar - m00i*ai + m01r*br - m01i*bi;
        si[m0] = m00r*ai + m00i*ar + m01r*bi + m01i*br;
        sr[m1] = m10r*ar - m10i*ai + m11r*br - m11i*bi;
        si[m1] = m10r*ai + m10i*ar + m11r*bi + m11i*br;
    }
}

template<int BC, int BT>
__device__ __forceinline__ void apply_cnot(float* sr, float* si) {
    #pragma unroll
    for (int m = 0; m < 16; ++m) {
        if ((m & BC) && !(m & BT)) {
            const int m2 = m | BT;
            float t;
            t = sr[m]; sr[m] = sr[m2]; sr[m2] = t;
            t = si[m]; si[m] = si[m2]; si[m2] = t;
        }
    }
}

template<int I0, int I1>
__device__ __forceinline__ void rot_pair(float* sr, float* si, float c, float s) {
    const float r0 = sr[I0], r1 = sr[I1];
    sr[I0] = c*r0 - s*r1;
    sr[I1] = s*r0 + c*r1;
    const float i0 = si[I0], i1 = si[I1];
    si[I0] = c*i0 - s*i1;
    si[I1] = s*i0 + c*i1;
}

// c = cos(alpha/2) = sqrt(1 - r^2), s = sin(alpha/2) = r, r = sqrt(num/den)
__device__ __forceinline__ void angle_cs(float num, float den, float& c, float& s) {
    const bool safe = den > 1e-20f;
    const float r2 = safe ? fminf(num / den, 1.0f) : 0.0f;
    s = sqrtf(r2);
    c = sqrtf(fmaxf(1.0f - r2, 0.0f));
}

__global__ __launch_bounds__(256) void qconv_kernel(
        const float* __restrict__ x,     // (32, 4, 64, 64)
        const float* __restrict__ wts,   // (4, 2, 4, 3)
        float* __restrict__ out) {       // (32, 16, 64, 64)
    // --- 32 Rot matrices (ic, l, wq) -> 2x2 complex, built once per block ---
    __shared__ float smat[32 * 8];
    const int tid = threadIdx.x;
    if (tid < 32) {
        const float phi   = wts[tid*3 + 0];
        const float theta = wts[tid*3 + 1];
        const float omega = wts[tid*3 + 2];
        float st, ct; __sincosf(0.5f * theta,         &st, &ct);
        float sA, cA; __sincosf(0.5f * (phi + omega), &sA, &cA); // ep = cA - i sA
        float sB, cB; __sincosf(0.5f * (phi - omega), &sB, &cB); // em = cB + i sB
        float* m = &smat[tid * 8];
        m[0] =  cA * ct;  m[1] = -sA * ct;   // m00 = ep*ct
        m[2] = -cB * st;  m[3] = -sB * st;   // m01 = -em*st
        m[4] =  cB * st;  m[5] = -sB * st;   // m10 = conj(em)*st
        m[6] =  cA * ct;  m[7] =  sA * ct;   // m11 = conj(ep)*ct
    }
    __syncthreads();

    const int gid = blockIdx.x * 256 + tid;      // 0 .. 131071
    const int b  = gid >> 12;
    const int y  = (gid >> 6) & 63;
    const int xc = gid & 63;
    const float* xb = x + (size_t)b * (4 * 4096);

    float sr[16], si[16];
    #pragma unroll
    for (int i = 0; i < 16; ++i) { sr[i] = 0.0f; si[i] = 0.0f; }
    sr[0] = 1.0f;

    #pragma unroll 1
    for (int ic = 0; ic < 4; ++ic) {
        // ---- load 3x3 patch (pad value 0.01), square it ----
        const float* xcp = xb + ic * 4096;
        float q[9];
        float S = 0.0f;
        #pragma unroll
        for (int dy = 0; dy < 3; ++dy) {
            const int yy = y - 1 + dy;
            #pragma unroll
            for (int dx = 0; dx < 3; ++dx) {
                const int xx = xc - 1 + dx;
                const bool in = (yy >= 0) && (yy < 64) && (xx >= 0) && (xx < 64);
                const float v = in ? xcp[yy * 64 + xx] : 0.01f;
                const float vv = v * v;
                q[dy * 3 + dx] = vv;
                S += vv;
            }
        }
        // normalized a2[j] = q[j] * scale2 (j<9), zero for j>=9
        const float scale2 = 1.0f / fmaxf(S, 1e-24f);

        // ---- Mottonen multiplexed-RY angles (only non-identity ones) ----
        const float s01 = q[0] + q[1], s23 = q[2] + q[3];
        const float s45 = q[4] + q[5], s67 = q[6] + q[7];
        const float s03 = s01 + s23, s47 = s45 + s67;
        const float s07 = s03 + s47;
        float c0,  s0;  angle_cs(q[8] * scale2, (s07 + q[8]) * scale2, c0,  s0);  // t=0
        float c1,  s1;  angle_cs(s47 * scale2,  s07 * scale2,          c1,  s1);  // t=1 b=0
        float c2a, s2a; angle_cs(s23 * scale2,  s03 * scale2,          c2a, s2a); // t=2 b=0
        float c2b, s2b; angle_cs(s67 * scale2,  s47 * scale2,          c2b, s2b); // t=2 b=1
        float c3a, s3a; angle_cs(q[1] * scale2, s01 * scale2,          c3a, s3a); // t=3 b=0
        float c3b, s3b; angle_cs(q[3] * scale2, s23 * scale2,          c3b, s3b); // t=3 b=1
        float c3c, s3c; angle_cs(q[5] * scale2, s45 * scale2,          c3c, s3c); // t=3 b=2
        float c3d, s3d; angle_cs(q[7] * scale2, s67 * scale2,          c3d, s3d); // t=3 b=3

        // ---- apply cascade: t=0 (pairs j,j+8) ----
        rot_pair<0, 8>(sr, si, c0, s0);  rot_pair<1, 9>(sr, si, c0, s0);
        rot_pair<2,10>(sr, si, c0, s0);  rot_pair<3,11>(sr, si, c0, s0);
        rot_pair<4,12>(sr, si, c0, s0);  rot_pair<5,13>(sr, si, c0, s0);
        rot_pair<6,14>(sr, si, c0, s0);  rot_pair<7,15>(sr, si, c0, s0);
        // t=1 b=0 (pairs j,j+4)  [b=1 identity: num=0]
        rot_pair<0, 4>(sr, si, c1, s1);  rot_pair<1, 5>(sr, si, c1, s1);
        rot_pair<2, 6>(sr, si, c1, s1);  rot_pair<3, 7>(sr, si, c1, s1);
        // t=2 b=0,1  [b=2,3 identity]
        rot_pair<0, 2>(sr, si, c2a, s2a); rot_pair<1, 3>(sr, si, c2a, s2a);
        rot_pair<4, 6>(sr, si, c2b, s2b); rot_pair<5, 7>(sr, si, c2b, s2b);
        // t=3 b=0..3  [b=4..7 identity]
        rot_pair<0, 1>(sr, si, c3a, s3a); rot_pair<2, 3>(sr, si, c3b, s3b);
        rot_pair<4, 5>(sr, si, c3c, s3c); rot_pair<6, 7>(sr, si, c3d, s3d);

        // ---- 2 entangling layers of Rot gates + CNOT rings ----
        const float* mb = &smat[ic * 64];
        #define GATE(STRIDE, OFF) apply_gate<STRIDE>(sr, si, \
            mb[(OFF)+0], mb[(OFF)+1], mb[(OFF)+2], mb[(OFF)+3], \
            mb[(OFF)+4], mb[(OFF)+5], mb[(OFF)+6], mb[(OFF)+7])
        // layer 0: gates wq=0..3 (stride 8,4,2,1), then CNOT(i, i+1)
        GATE(8,  0); GATE(4,  8); GATE(2, 16); GATE(1, 24);
        apply_cnot<8, 4>(sr, si);  // CNOT(0,1)
        apply_cnot<4, 2>(sr, si);  // CNOT(1,2)
        apply_cnot<2, 1>(sr, si);  // CNOT(2,3)
        apply_cnot<1, 8>(sr, si);  // CNOT(3,0)
        // layer 1: then CNOT(i, i+2)
        GATE(8, 32); GATE(4, 40); GATE(2, 48); GATE(1, 56);
        apply_cnot<8, 2>(sr, si);  // CNOT(0,2)
        apply_cnot<4, 1>(sr, si);  // CNOT(1,3)
        apply_cnot<2, 8>(sr, si);  // CNOT(2,0)
        apply_cnot<1, 4>(sr, si);  // CNOT(3,1)
        #undef GATE
    }

    // ---- probabilities -> clipped output, (b, 16, 64, 64) ----
    float* ob = out + (size_t)b * (16 * 4096) + y * 64 + xc;
    #pragma unroll
    for (int m = 0; m < 16; ++m) {
        const float p = sr[m]*sr[m] + si[m]*si[m];
        ob[m * 4096] = fminf(p * 8.0f, 1.0f);
    }
}

extern "C" void kernel_launch(void* const* d_in, const int* in_sizes, int n_in,
                              void* d_out, int out_size, void* d_ws, size_t ws_size,
                              hipStream_t stream) {
    const float* x   = (const float*)d_in[0];
    const float* wts = (const float*)d_in[1];
    float* out = (float*)d_out;
    // N = 32*64*64 = 131072 pixels, one thread each
    qconv_kernel<<<512, 256, 0, stream>>>(x, wts, out);
}

// Round 2
// 22.582 us; speedup vs baseline: 1.5019x; 1.5019x over previous
//
#include <hip/hip_runtime.h>

// ---------------------------------------------------------------------------
// Quantum conv2d: per output pixel, simulate a 4-wire (16-dim) circuit.
// State kept entirely in registers; all indices compile-time; native
// v_sqrt/v_rsq for the Mottonen angles (normalization cancels in the ratios).
// ---------------------------------------------------------------------------

template<int STRIDE>
__device__ __forceinline__ void apply_gate(float* sr, float* si,
                                           const float4 A, const float4 B) {
    // m00 = (A.x,A.y), m01 = (A.z,A.w), m10 = (B.x,B.y), m11 = (B.z,B.w)
    #pragma unroll
    for (int m0 = 0; m0 < 16; ++m0) {
        if (m0 & STRIDE) continue;
        const int m1 = m0 | STRIDE;
        const float ar = sr[m0], ai = si[m0], br = sr[m1], bi = si[m1];
        sr[m0] = A.x*ar - A.y*ai + A.z*br - A.w*bi;
        si[m0] = A.x*ai + A.y*ar + A.z*bi + A.w*br;
        sr[m1] = B.x*ar - B.y*ai + B.z*br - B.w*bi;
        si[m1] = B.x*ai + B.y*ar + B.z*bi + B.w*br;
    }
}

template<int BC, int BT>
__device__ __forceinline__ void apply_cnot(float* sr, float* si) {
    #pragma unroll
    for (int m = 0; m < 16; ++m) {
        if ((m & BC) && !(m & BT)) {
            const int m2 = m | BT;
            float t;
            t = sr[m]; sr[m] = sr[m2]; sr[m2] = t;
            t = si[m]; si[m] = si[m2]; si[m2] = t;
        }
    }
}

template<int I0, int I1>
__device__ __forceinline__ void rot_pair(float* sr, float* si, float c, float s) {
    const float r0 = sr[I0], r1 = sr[I1];
    sr[I0] = c*r0 - s*r1;
    sr[I1] = s*r0 + c*r1;
    const float i0 = si[I0], i1 = si[I1];
    si[I0] = c*i0 - s*i1;
    si[I1] = s*i0 + c*i1;
}

// Multiplexed-RY node: children sums (lo, hi), un-normalized (scale cancels).
// c = sqrt(lo/(lo+hi)), s = sqrt(hi/(lo+hi)); identity when den ~ 0.
__device__ __forceinline__ void node_cs(float lo, float hi, float& c, float& s) {
    const float den = lo + hi;
    const bool ok = den > 1e-30f;
    const float rs = __builtin_amdgcn_rsqf(fmaxf(den, 1e-37f));
    c = ok ? __builtin_amdgcn_sqrtf(lo) * rs : 1.0f;
    s = ok ? __builtin_amdgcn_sqrtf(hi) * rs : 0.0f;
}

// Mottonen RY cascade applied to a dense register state (channels 1..3).
__device__ __forceinline__ void cascade(float* sr, float* si, const float* Q) {
    const float s01 = Q[0]+Q[1], s23 = Q[2]+Q[3];
    const float s45 = Q[4]+Q[5], s67 = Q[6]+Q[7];
    const float s03 = s01+s23, s47 = s45+s67, s07 = s03+s47;
    float c0, s0;  node_cs(s07,  Q[8], c0,  s0);   // t=0
    float c1, s1;  node_cs(s03,  s47,  c1,  s1);   // t=1 b=0 (b=1 identity)
    float c2a,s2a; node_cs(s01,  s23,  c2a, s2a);  // t=2 b=0
    float c2b,s2b; node_cs(s45,  s67,  c2b, s2b);  // t=2 b=1 (b=2,3 identity)
    float c3a,s3a; node_cs(Q[0], Q[1], c3a, s3a);  // t=3 b=0
    float c3b,s3b; node_cs(Q[2], Q[3], c3b, s3b);  // t=3 b=1
    float c3c,s3c; node_cs(Q[4], Q[5], c3c, s3c);  // t=3 b=2
    float c3d,s3d; node_cs(Q[6], Q[7], c3d, s3d);  // t=3 b=3 (b=4..7 identity)

    rot_pair<0, 8>(sr, si, c0, s0);  rot_pair<1, 9>(sr, si, c0, s0);
    rot_pair<2,10>(sr, si, c0, s0);  rot_pair<3,11>(sr, si, c0, s0);
    rot_pair<4,12>(sr, si, c0, s0);  rot_pair<5,13>(sr, si, c0, s0);
    rot_pair<6,14>(sr, si, c0, s0);  rot_pair<7,15>(sr, si, c0, s0);
    rot_pair<0, 4>(sr, si, c1, s1);  rot_pair<1, 5>(sr, si, c1, s1);
    rot_pair<2, 6>(sr, si, c1, s1);  rot_pair<3, 7>(sr, si, c1, s1);
    rot_pair<0, 2>(sr, si, c2a, s2a); rot_pair<1, 3>(sr, si, c2a, s2a);
    rot_pair<4, 6>(sr, si, c2b, s2b); rot_pair<5, 7>(sr, si, c2b, s2b);
    rot_pair<0, 1>(sr, si, c3a, s3a); rot_pair<2, 3>(sr, si, c3b, s3b);
    rot_pair<4, 5>(sr, si, c3c, s3c); rot_pair<6, 7>(sr, si, c3d, s3d);
}

// One channel's fixed circuit: 4 Rot gates + CNOT(i,i+1) ring, then
// 4 Rot gates + CNOT(i,i+2) ring.  mb -> 16 float4 (8 matrices).
__device__ __forceinline__ void channel_gates(float* sr, float* si,
                                              const float* mb) {
    const float4* m4 = (const float4*)mb;
    apply_gate<8>(sr, si, m4[0],  m4[1]);
    apply_gate<4>(sr, si, m4[2],  m4[3]);
    apply_gate<2>(sr, si, m4[4],  m4[5]);
    apply_gate<1>(sr, si, m4[6],  m4[7]);
    apply_cnot<8, 4>(sr, si);  apply_cnot<4, 2>(sr, si);
    apply_cnot<2, 1>(sr, si);  apply_cnot<1, 8>(sr, si);
    apply_gate<8>(sr, si, m4[8],  m4[9]);
    apply_gate<4>(sr, si, m4[10], m4[11]);
    apply_gate<2>(sr, si, m4[12], m4[13]);
    apply_gate<1>(sr, si, m4[14], m4[15]);
    apply_cnot<8, 2>(sr, si);  apply_cnot<4, 1>(sr, si);
    apply_cnot<2, 8>(sr, si);  apply_cnot<1, 4>(sr, si);
}

__global__ __launch_bounds__(256) void qconv_kernel(
        const float* __restrict__ x,     // (32, 4, 64, 64)
        const float* __restrict__ wts,   // (4, 2, 4, 3)
        float* __restrict__ out) {       // (32, 16, 64, 64)
    // --- 32 Rot matrices (ic, l, wq) -> 2x2 complex, built once per block ---
    __shared__ float smat[32 * 8];
    const int tid = threadIdx.x;
    if (tid < 32) {
        const float phi   = wts[tid*3 + 0];
        const float theta = wts[tid*3 + 1];
        const float omega = wts[tid*3 + 2];
        float st, ct; __sincosf(0.5f * theta,         &st, &ct);
        float sA, cA; __sincosf(0.5f * (phi + omega), &sA, &cA); // ep = cA - i sA
        float sB, cB; __sincosf(0.5f * (phi - omega), &sB, &cB); // em = cB + i sB
        float* m = &smat[tid * 8];
        m[0] =  cA * ct;  m[1] = -sA * ct;   // m00 = ep*ct
        m[2] = -cB * st;  m[3] = -sB * st;   // m01 = -em*st
        m[4] =  cB * st;  m[5] = -sB * st;   // m10 = conj(em)*st
        m[6] =  cA * ct;  m[7] =  sA * ct;   // m11 = conj(ep)*ct
    }
    __syncthreads();

    const int gid = blockIdx.x * 256 + tid;      // 0 .. 131071
    const int b  = gid >> 12;
    const int y  = (gid >> 6) & 63;
    const int xc = gid & 63;
    const float* xb = x + (size_t)b * (4 * 4096);

    // --- hoisted 3x3 patch geometry (shared across channels) ---
    int  off[9];
    bool inb[9];
    #pragma unroll
    for (int dy = 0; dy < 3; ++dy) {
        #pragma unroll
        for (int dx = 0; dx < 3; ++dx) {
            const int yy = y - 1 + dy, xx = xc - 1 + dx;
            inb[dy*3+dx] = ((unsigned)yy < 64u) && ((unsigned)xx < 64u);
            const int yyc = min(max(yy, 0), 63);
            const int xxc = min(max(xx, 0), 63);
            off[dy*3+dx] = yyc * 64 + xxc;
        }
    }

    // --- load all 4 channels' patches up front, square them ---
    float q[4][9];
    #pragma unroll
    for (int ic = 0; ic < 4; ++ic) {
        const float* base = xb + ic * 4096;
        #pragma unroll
        for (int j = 0; j < 9; ++j) {
            const float v = inb[j] ? base[off[j]] : 0.01f;
            q[ic][j] = v * v;
        }
    }

    float sr[16], si[16];
    #pragma unroll
    for (int i = 0; i < 16; ++i) { sr[i] = 0.0f; si[i] = 0.0f; }

    // --- channel 0: Mottonen on |0> yields amplitudes directly ---
    {
        const float* Q = q[0];
        const float S = ((Q[0]+Q[1]) + (Q[2]+Q[3])) +
                        ((Q[4]+Q[5]) + (Q[6]+Q[7])) + Q[8];
        const bool ok = S > 1e-30f;
        const float rs = __builtin_amdgcn_rsqf(fmaxf(S, 1e-37f));
        #pragma unroll
        for (int j = 0; j < 9; ++j) {
            const float a = __builtin_amdgcn_sqrtf(Q[j]) * rs;
            sr[j] = ok ? a : (j == 0 ? 1.0f : 0.0f);
        }
        // si stays 0 -> compiler folds imaginary half of the first gate layer
    }
    channel_gates(sr, si, &smat[0]);

    // --- channels 1..3: full cascade on dense state, then gates ---
    #pragma unroll
    for (int ic = 1; ic < 4; ++ic) {
        cascade(sr, si, q[ic]);
        channel_gates(sr, si, &smat[ic * 64]);
    }

    // --- probabilities -> clipped output, (b, 16, 64, 64) ---
    float* ob = out + (size_t)b * (16 * 4096) + y * 64 + xc;
    #pragma unroll
    for (int m = 0; m < 16; ++m) {
        const float p = sr[m]*sr[m] + si[m]*si[m];
        ob[m * 4096] = fminf(p * 8.0f, 1.0f);
    }
}

extern "C" void kernel_launch(void* const* d_in, const int* in_sizes, int n_in,
                              void* d_out, int out_size, void* d_ws, size_t ws_size,
                              hipStream_t stream) {
    const float* x   = (const float*)d_in[0];
    const float* wts = (const float*)d_in[1];
    float* out = (float*)d_out;
    qconv_kernel<<<512, 256, 0, stream>>>(x, wts, out);
}

// Round 3
// 20.183 us; speedup vs baseline: 1.6804x; 1.1188x over previous
//
#include <hip/hip_runtime.h>

// ---------------------------------------------------------------------------
// Quantum conv2d, packed-fp32 edition.
// State: f2[16] (re,im) per thread -> complex MAC = 2x v_pk_fma_f32.
// Gate matrices pre-packed in LDS as {re,re,-im,im} per 2x2 entry.
// Input tile staged in LDS (6 rows x 64 cols x 4 ch) per 256-thread block.
// ---------------------------------------------------------------------------

typedef float f2 __attribute__((ext_vector_type(2)));

__device__ __forceinline__ f2 pkfma(f2 a, f2 b, f2 c) {
    return __builtin_elementwise_fma(a, b, c);
}
__device__ __forceinline__ f2 swap2(f2 v) {
    return __builtin_shufflevector(v, v, 1, 0);
}

struct GateM { f2 m00rr, m00ni, m01rr, m01ni, m10rr, m10ni, m11rr, m11ni; };

__device__ __forceinline__ GateM load_gate(const float* gp) {
    const float4* p = (const float4*)gp;
    const float4 e0 = p[0], e1 = p[1], e2 = p[2], e3 = p[3];
    GateM G;
    G.m00rr = f2{e0.x, e0.y}; G.m00ni = f2{e0.z, e0.w};
    G.m01rr = f2{e1.x, e1.y}; G.m01ni = f2{e1.z, e1.w};
    G.m10rr = f2{e2.x, e2.y}; G.m10ni = f2{e2.z, e2.w};
    G.m11rr = f2{e3.x, e3.y}; G.m11ni = f2{e3.z, e3.w};
    return G;
}

template<int STRIDE>
__device__ __forceinline__ void apply_gate(f2* s, const GateM G) {
    #pragma unroll
    for (int m0 = 0; m0 < 16; ++m0) {
        if (m0 & STRIDE) continue;
        const int m1 = m0 | STRIDE;
        const f2 a = s[m0], b = s[m1];
        const f2 as = swap2(a), bs = swap2(b);
        f2 o0 = G.m00rr * a;
        o0 = pkfma(G.m00ni, as, o0);
        o0 = pkfma(G.m01rr, b,  o0);
        o0 = pkfma(G.m01ni, bs, o0);
        f2 o1 = G.m10rr * a;
        o1 = pkfma(G.m10ni, as, o1);
        o1 = pkfma(G.m11rr, b,  o1);
        o1 = pkfma(G.m11ni, bs, o1);
        s[m0] = o0; s[m1] = o1;
    }
}

template<int BC, int BT>
__device__ __forceinline__ void apply_cnot(f2* s) {
    #pragma unroll
    for (int m = 0; m < 16; ++m) {
        if ((m & BC) && !(m & BT)) {
            const int m2 = m | BT;
            const f2 t = s[m]; s[m] = s[m2]; s[m2] = t;
        }
    }
}

struct Node { f2 cc, ss, ns; };

// Multiplexed-RY node from un-normalized child sums (scale cancels).
__device__ __forceinline__ Node node_cs(float lo, float hi) {
    const float den = lo + hi;
    const bool ok = den > 1e-30f;
    const float rs = __builtin_amdgcn_rsqf(fmaxf(den, 1e-37f));
    const float c = ok ? __builtin_amdgcn_sqrtf(lo) * rs : 1.0f;
    const float s = ok ? __builtin_amdgcn_sqrtf(hi) * rs : 0.0f;
    return Node{f2{c, c}, f2{s, s}, f2{-s, -s}};
}

template<int I0, int I1>
__device__ __forceinline__ void rot_pair(f2* s, const Node& n) {
    const f2 a = s[I0], b = s[I1];
    s[I0] = pkfma(n.cc, a, n.ns * b);
    s[I1] = pkfma(n.ss, a, n.cc * b);
}

__device__ __forceinline__ void cascade(f2* s, const float* Q) {
    const float s01 = Q[0]+Q[1], s23 = Q[2]+Q[3];
    const float s45 = Q[4]+Q[5], s67 = Q[6]+Q[7];
    const float s03 = s01+s23, s47 = s45+s67, s07 = s03+s47;
    const Node n0  = node_cs(s07,  Q[8]);   // t=0
    const Node n1  = node_cs(s03,  s47);    // t=1 b=0 (b=1 identity)
    const Node n2a = node_cs(s01,  s23);    // t=2 b=0
    const Node n2b = node_cs(s45,  s67);    // t=2 b=1 (b=2,3 identity)
    const Node n3a = node_cs(Q[0], Q[1]);   // t=3 b=0
    const Node n3b = node_cs(Q[2], Q[3]);   // t=3 b=1
    const Node n3c = node_cs(Q[4], Q[5]);   // t=3 b=2
    const Node n3d = node_cs(Q[6], Q[7]);   // t=3 b=3 (b=4..7 identity)

    rot_pair<0, 8>(s, n0);  rot_pair<1, 9>(s, n0);
    rot_pair<2,10>(s, n0);  rot_pair<3,11>(s, n0);
    rot_pair<4,12>(s, n0);  rot_pair<5,13>(s, n0);
    rot_pair<6,14>(s, n0);  rot_pair<7,15>(s, n0);
    rot_pair<0, 4>(s, n1);  rot_pair<1, 5>(s, n1);
    rot_pair<2, 6>(s, n1);  rot_pair<3, 7>(s, n1);
    rot_pair<0, 2>(s, n2a); rot_pair<1, 3>(s, n2a);
    rot_pair<4, 6>(s, n2b); rot_pair<5, 7>(s, n2b);
    rot_pair<0, 1>(s, n3a); rot_pair<2, 3>(s, n3b);
    rot_pair<4, 5>(s, n3c); rot_pair<6, 7>(s, n3d);
}

// Gates 1..7 of a channel (after the wire-0 gate) + both CNOT rings.
// cb -> this channel's 8 gates, 16 floats each.
__device__ __forceinline__ void gates_tail(f2* s, const float* cb) {
    apply_gate<4>(s, load_gate(cb + 1*16));
    apply_gate<2>(s, load_gate(cb + 2*16));
    apply_gate<1>(s, load_gate(cb + 3*16));
    apply_cnot<8, 4>(s); apply_cnot<4, 2>(s);
    apply_cnot<2, 1>(s); apply_cnot<1, 8>(s);
    apply_gate<8>(s, load_gate(cb + 4*16));
    apply_gate<4>(s, load_gate(cb + 5*16));
    apply_gate<2>(s, load_gate(cb + 6*16));
    apply_gate<1>(s, load_gate(cb + 7*16));
    apply_cnot<8, 2>(s); apply_cnot<4, 1>(s);
    apply_cnot<2, 8>(s); apply_cnot<1, 4>(s);
}

// Read one channel's squared 3x3 patch from the LDS tile [6][4][64].
__device__ __forceinline__ void read_q(const float* tile, int ic, int ly,
                                       int xc, float* q) {
    #pragma unroll
    for (int dy = 0; dy < 3; ++dy) {
        const float* row = tile + ((ly + dy) * 4 + ic) * 64;
        #pragma unroll
        for (int dx = 0; dx < 3; ++dx) {
            const int col = xc - 1 + dx;
            const int colc = min(max(col, 0), 63);
            float v = row[colc];
            v = ((unsigned)col < 64u) ? v : 0.01f;
            q[dy*3 + dx] = v * v;
        }
    }
}

__global__ __launch_bounds__(256) void qconv_kernel(
        const float* __restrict__ x,     // (32, 4, 64, 64)
        const float* __restrict__ wts,   // (4, 2, 4, 3)
        float* __restrict__ out) {       // (32, 16, 64, 64)
    __shared__ float smat[32 * 16];      // 2 KB: 32 gates x 4 entries x {re,re,-im,im}
    __shared__ float tile[6 * 4 * 64];   // 6 KB: rows y0-1..y0+4, 4 channels

    const int tid = threadIdx.x;
    const int blk = blockIdx.x;
    const int b  = blk >> 4;             // image
    const int y0 = (blk & 15) << 2;      // first of 4 rows

    // --- build packed Rot matrices (one thread per gate) ---
    if (tid < 32) {
        const float phi   = wts[tid*3 + 0];
        const float theta = wts[tid*3 + 1];
        const float omega = wts[tid*3 + 2];
        float st, ct; __sincosf(0.5f * theta,         &st, &ct);
        float sA, cA; __sincosf(0.5f * (phi + omega), &sA, &cA);
        float sB, cB; __sincosf(0.5f * (phi - omega), &sB, &cB);
        float* g = &smat[tid * 16];
        // entry e: {re, re, -im, im}
        // m00 = (cA*ct, -sA*ct)
        g[0]  =  cA*ct; g[1]  =  cA*ct; g[2]  =  sA*ct; g[3]  = -sA*ct;
        // m01 = (-cB*st, -sB*st)
        g[4]  = -cB*st; g[5]  = -cB*st; g[6]  =  sB*st; g[7]  = -sB*st;
        // m10 = (cB*st, -sB*st)
        g[8]  =  cB*st; g[9]  =  cB*st; g[10] =  sB*st; g[11] = -sB*st;
        // m11 = (cA*ct, sA*ct)
        g[12] =  cA*ct; g[13] =  cA*ct; g[14] = -sA*ct; g[15] =  sA*ct;
    }

    // --- stage input tile (coalesced), pad rows with 0.01 ---
    const float* xb = x + (size_t)b * 16384;
    #pragma unroll
    for (int i = 0; i < 6; ++i) {
        const int e = tid + i * 256;          // [r][ch][col]
        const int r = e >> 8, ch = (e >> 6) & 3, col = e & 63;
        const int gy = y0 - 1 + r;
        float v = 0.01f;
        if ((unsigned)gy < 64u) v = xb[ch * 4096 + gy * 64 + col];
        tile[e] = v;
    }
    __syncthreads();

    const int ly = tid >> 6, xc = tid & 63;

    f2 s[16];

    // --- channel 0: Mottonen on |0> gives real amplitudes directly ---
    {
        float q0[9];
        read_q(tile, 0, ly, xc, q0);
        const float S = ((q0[0]+q0[1]) + (q0[2]+q0[3])) +
                        ((q0[4]+q0[5]) + (q0[6]+q0[7])) + q0[8];
        const bool ok = S > 1e-30f;
        const float rs = __builtin_amdgcn_rsqf(fmaxf(S, 1e-37f));
        float ar[9];
        #pragma unroll
        for (int j = 0; j < 9; ++j) {
            const float a = __builtin_amdgcn_sqrtf(q0[j]) * rs;
            ar[j] = ok ? a : (j == 0 ? 1.0f : 0.0f);
        }
        // wire-0 gate (stride 8) on a real, 9-sparse state: defines all of s[]
        const float4* p = (const float4*)smat;
        const float4 e0 = p[0], e1 = p[1], e2 = p[2], e3 = p[3];
        const f2 m00 = f2{e0.x, e0.w};   // (re, im)
        const f2 m01 = f2{e1.x, e1.w};
        const f2 m10 = f2{e2.x, e2.w};
        const f2 m11 = f2{e3.x, e3.w};
        s[0] = pkfma(f2{ar[8], ar[8]}, m01, f2{ar[0], ar[0]} * m00);
        s[8] = pkfma(f2{ar[8], ar[8]}, m11, f2{ar[0], ar[0]} * m10);
        #pragma unroll
        for (int j = 1; j < 8; ++j) {
            s[j]     = f2{ar[j], ar[j]} * m00;
            s[j + 8] = f2{ar[j], ar[j]} * m10;
        }
    }
    gates_tail(s, smat);

    // --- channels 1..3: cascade + full gate block ---
    #pragma unroll
    for (int ic = 1; ic < 4; ++ic) {
        float q[9];
        read_q(tile, ic, ly, xc, q);
        cascade(s, q);
        const float* cb = smat + ic * 128;
        apply_gate<8>(s, load_gate(cb));
        gates_tail(s, cb);
    }

    // --- probabilities -> clipped output, (b, 16, 64, 64) ---
    float* ob = out + (size_t)b * (16 * 4096) + (y0 + ly) * 64 + xc;
    #pragma unroll
    for (int m = 0; m < 16; ++m) {
        const float p = s[m].x * s[m].x + s[m].y * s[m].y;
        ob[m * 4096] = fminf(p * 8.0f, 1.0f);
    }
}

extern "C" void kernel_launch(void* const* d_in, const int* in_sizes, int n_in,
                              void* d_out, int out_size, void* d_ws, size_t ws_size,
                              hipStream_t stream) {
    const float* x   = (const float*)d_in[0];
    const float* wts = (const float*)d_in[1];
    float* out = (float*)d_out;
    qconv_kernel<<<512, 256, 0, stream>>>(x, wts, out);
}